// Round 2
// baseline (93.791 us; speedup 1.0000x reference)
//
#include <hip/hip_runtime.h>
#include <stdint.h>

// ---------------------------------------------------------------------------
// NT-Xent loss, B=8 S=512 D=128  ->  N=4096, 2N=8192 rows, K=128.
// loss = mean_i( -pos_i + log(sum_{j!=i} exp(sim_ij)) ),  sim = z_n z_n^T / T
//
//  k1: normalize rows (fp32), pos in fp32, store z_n*SCALE bf16 where
//      SCALE^2 = log2(e)/T  -> MFMA acc is sim*log2e, exp(sim)=exp2(acc).
//      Also zeroes rowsum.
//  k2: symmetric Gram: 64x64 grid of 128x128 supertiles, only bj>=bi live
//      (2080 blocks). Off-diag blocks add exp to row sums AND (transpose)
//      col sums; diag blocks add row sums only, excluding the diagonal
//      element exactly. B tile (128 cols x 128 K) in LDS, +16B row pad.
//      16x16x32 bf16 MFMA, 4 waves x 32 rows, one barrier per block.
//  k3: loss = (sum_i log(rowsum_i) - 2*sum pos_half) / 8192.
// No max-subtraction needed: logits in [-14.3,14.3], sums < 1.3e10.
// ---------------------------------------------------------------------------

#define TOTAL   8192
#define NHALF   4096
#define DK      128
#define TEMP_INV 14.285714285714286f
#define SCALE    4.539816f      // sqrt(log2(e)/0.07)
#define TILE    128

typedef short  bf16x8  __attribute__((ext_vector_type(8)));
typedef float  floatx4 __attribute__((ext_vector_type(4)));

#if __has_builtin(__builtin_amdgcn_exp2f)
#define EXP2(x) __builtin_amdgcn_exp2f(x)
#else
#define EXP2(x) exp2f(x)
#endif

__device__ __forceinline__ uint32_t f2bf(float f) {
  uint32_t u = __float_as_uint(f);
  return (u + 0x7fffu + ((u >> 16) & 1u)) >> 16;   // RNE; inputs finite
}
__device__ __forceinline__ uint32_t pack2bf(float lo, float hi) {
  return f2bf(lo) | (f2bf(hi) << 16);
}

// --------------------------- kernel 1: normalize ---------------------------
__global__ __launch_bounds__(256) void ntx_norm(
    const float* __restrict__ zi, const float* __restrict__ zj,
    uint32_t* __restrict__ zn,   // packed 2xbf16, [TOTAL][64]
    float* __restrict__ pos,     // [NHALF]
    float* __restrict__ rowsum)  // [TOTAL], zeroed here
{
  const int t = threadIdx.x;
  if (blockIdx.x < 32) rowsum[blockIdx.x * 256 + t] = 0.0f;

  const int wave = t >> 6, lane = t & 63;
  const int i = blockIdx.x * 4 + wave;

  const float2 vi = *(const float2*)(zi + (size_t)i * DK + lane * 2);
  const float2 vj = *(const float2*)(zj + (size_t)i * DK + lane * 2);
  float ssi = vi.x * vi.x + vi.y * vi.y;
  float ssj = vj.x * vj.x + vj.y * vj.y;
  float dij = vi.x * vj.x + vi.y * vj.y;
#pragma unroll
  for (int m = 1; m <= 32; m <<= 1) {
    ssi += __shfl_xor(ssi, m, 64);
    ssj += __shfl_xor(ssj, m, 64);
    dij += __shfl_xor(dij, m, 64);
  }
  const float invi = 1.0f / fmaxf(sqrtf(ssi), 1e-12f);
  const float invj = 1.0f / fmaxf(sqrtf(ssj), 1e-12f);

  zn[(size_t)i * 64 + lane] =
      pack2bf(vi.x * invi * SCALE, vi.y * invi * SCALE);
  zn[(size_t)(i + NHALF) * 64 + lane] =
      pack2bf(vj.x * invj * SCALE, vj.y * invj * SCALE);
  if (lane == 0) pos[i] = dij * invi * invj * TEMP_INV;
}

// ---------------- kernel 2: symmetric Gram + exp row-sums ------------------
// grid (64,64) x 256; blocks with bj<bi exit immediately (triangle).
__global__ __launch_bounds__(256, 4) void ntx_gemm(
    const uint16_t* __restrict__ z,   // [TOTAL][DK] bf16 (scaled)
    float* __restrict__ rowsum)
{
  const int bi = blockIdx.x, bj = blockIdx.y;
  if (bj < bi) return;

  __shared__ uint4 lb4[TILE * 17];    // 128 cols x (256B data + 16B pad)

  const int t = threadIdx.x;
  const int wave = t >> 6, lane = t & 63;
  const int q = lane >> 4, c = lane & 15;
  const int I0 = bi * TILE, J0 = bj * TILE;
  const int rowbase = I0 + wave * 32;
  const bool diagblk = (bi == bj);

  // stage B tile (coalesced: 16 lanes cover one 256B row)
  {
    const int ch = t & 15, r0 = t >> 4;
#pragma unroll
    for (int p = 0; p < 8; ++p) {
      const int r = r0 + p * 16;
      lb4[r * 17 + ch] = *(const uint4*)(z + (size_t)(J0 + r) * DK + ch * 8);
    }
  }

  // A fragments: 2 strips x 4 k-steps.  A[m=c][k=q*8+j]
  bf16x8 afrag[2][4];
#pragma unroll
  for (int s = 0; s < 2; ++s) {
    const uint16_t* ap = z + (size_t)(rowbase + s * 16 + c) * DK + q * 8;
#pragma unroll
    for (int kk = 0; kk < 4; ++kk)
      afrag[s][kk] = *(const bf16x8*)(ap + kk * 32);
  }

  float runsum[2][4] = {{0.f, 0.f, 0.f, 0.f}, {0.f, 0.f, 0.f, 0.f}};
  float colacc[8];

  __syncthreads();

#pragma unroll
  for (int jt = 0; jt < 8; ++jt) {
    // B[k=q*8+j][n=c] -> lds row (jt*16+c), uint4 (kk*4+q)
    bf16x8 bfrag[4];
#pragma unroll
    for (int kk = 0; kk < 4; ++kk)
      bfrag[kk] = *(const bf16x8*)&lb4[(jt * 16 + c) * 17 + kk * 4 + q];

    float cpart = 0.0f;
#pragma unroll
    for (int s = 0; s < 2; ++s) {
      floatx4 acc = {0.0f, 0.0f, 0.0f, 0.0f};
#pragma unroll
      for (int kk = 0; kk < 4; ++kk)
        acc = __builtin_amdgcn_mfma_f32_16x16x32_bf16(afrag[s][kk],
                                                      bfrag[kk], acc, 0, 0, 0);
      if (diagblk && (jt == wave * 2 + s)) {   // diagonal 16-tile (uniform)
#pragma unroll
        for (int r = 0; r < 4; ++r) {
          float e = EXP2(acc[r]);
          e = (q * 4 + r == c) ? 0.0f : e;
          runsum[s][r] += e;
          cpart += e;
        }
      } else {
#pragma unroll
        for (int r = 0; r < 4; ++r) {
          float e = EXP2(acc[r]);
          runsum[s][r] += e;
          cpart += e;
        }
      }
    }
    // column partial: sum over the 4 q-lane-groups (rows) -> all lanes
    cpart += __shfl_xor(cpart, 16, 64);
    cpart += __shfl_xor(cpart, 32, 64);
    colacc[jt] = cpart;
  }

  // row sums: reduce across the 16 c-lanes
#pragma unroll
  for (int s = 0; s < 2; ++s)
#pragma unroll
    for (int r = 0; r < 4; ++r) {
      float v = runsum[s][r];
      v += __shfl_xor(v, 1, 64);
      v += __shfl_xor(v, 2, 64);
      v += __shfl_xor(v, 4, 64);
      v += __shfl_xor(v, 8, 64);
      runsum[s][r] = v;
    }
  if (c == 0) {
#pragma unroll
    for (int s = 0; s < 2; ++s)
#pragma unroll
      for (int r = 0; r < 4; ++r)
        atomicAdd(&rowsum[rowbase + s * 16 + q * 4 + r], runsum[s][r]);
  }
  // transpose contribution (off-diagonal blocks only)
  if (!diagblk && q == 0) {
#pragma unroll
    for (int jt = 0; jt < 8; ++jt)
      atomicAdd(&rowsum[J0 + jt * 16 + c], colacc[jt]);
  }
}

// --------------------------- kernel 3: finalize ----------------------------
__global__ __launch_bounds__(1024) void ntx_final(
    const float* __restrict__ rowsum, const float* __restrict__ pos,
    float* __restrict__ out)
{
  const int t = threadIdx.x;
  float acc = 0.0f;
  for (int r = t; r < TOTAL; r += 1024) acc += __logf(rowsum[r]);
  for (int r = t; r < NHALF; r += 1024) acc -= 2.0f * pos[r];
#pragma unroll
  for (int m = 1; m <= 32; m <<= 1) acc += __shfl_xor(acc, m, 64);
  __shared__ float red[16];
  const int wave = t >> 6, lane = t & 63;
  if (lane == 0) red[wave] = acc;
  __syncthreads();
  if (t == 0) {
    float s = 0.0f;
#pragma unroll
    for (int w = 0; w < 16; ++w) s += red[w];
    out[0] = s / (float)TOTAL;
  }
}

// ---------------------------------------------------------------------------
extern "C" void kernel_launch(void* const* d_in, const int* in_sizes, int n_in,
                              void* d_out, int out_size, void* d_ws,
                              size_t ws_size, hipStream_t stream) {
  const float* zi = (const float*)d_in[0];
  const float* zj = (const float*)d_in[1];
  float* out = (float*)d_out;

  char* ws = (char*)d_ws;
  uint16_t* zn     = (uint16_t*)ws;                                    // 2 MB
  float*    rowsum = (float*)(ws + (size_t)TOTAL * DK * 2);            // 32 KB
  float*    pos    = (float*)(ws + (size_t)TOTAL * DK * 2 + TOTAL * 4);// 16 KB

  ntx_norm<<<dim3(NHALF / 4), dim3(256), 0, stream>>>(zi, zj, (uint32_t*)zn,
                                                      pos, rowsum);
  ntx_gemm<<<dim3(64, 64), dim3(256), 0, stream>>>(zn, rowsum);
  ntx_final<<<dim3(1), dim3(1024), 0, stream>>>(rowsum, pos, out);
}